// Round 1
// baseline (1253.949 us; speedup 1.0000x reference)
//
#include <hip/hip_runtime.h>
#include <math.h>

#define BATCH 2048
#define DIN   784
#define HID   512
#define NC    10
#define NS    10

constexpr int HP = HID + 1;        // 513 (ones column appended)
constexpr int M2 = NS * BATCH;     // 20480 batched rows for layers 2-4

// ---------------------------------------------------------------------------
// Dual GEMM: accm = A @ Wm ; accs = (A.*A) @ (drop*Ws)^2
// A: [M, lda] row-major (first K cols used). Wm/Ws: [K, N] row-major.
// If eps != nullptr (fused layers 2/3):
//     out[r*ldo + c] = leaky_relu(accm + sqrt(accs + 1e-12) * eps[r*N + c])
// else (layer 1):
//     out[r*N + c] = accm ; sgout[r*N + c] = sqrt(accs + 1e-12)
// ---------------------------------------------------------------------------
__global__ __launch_bounds__(256)
void dual_gemm64(const float* __restrict__ A, int lda,
                 const float* __restrict__ Wm,
                 const float* __restrict__ Ws,
                 const float* __restrict__ dropPtr,
                 int M, int N, int K,
                 const float* __restrict__ eps,
                 float* __restrict__ out, int ldo,
                 float* __restrict__ sgout)
{
    constexpr int BM = 64, BN = 64, BK = 16;
    __shared__ float As[BK][BM + 4];   // +4 pad: 16B-aligned rows, low conflicts
    __shared__ float Bm[BK][BN];
    __shared__ float Bs[BK][BN];

    const int tid = threadIdx.x;
    const int tx  = tid & 15;          // 0..15 col group
    const int ty  = tid >> 4;          // 0..15 row group
    const int lk  = tid & 15;          // A-load: k within tile
    const int lm  = tid >> 4;          // A-load: row group
    const int ln  = tid & 63;          // B-load: col
    const int lkb = tid >> 6;          // B-load: k group (0..3)

    const int row0 = blockIdx.y * BM;
    const int col0 = blockIdx.x * BN;

    const float drop = dropPtr ? dropPtr[0] : 1.0f;

    float accm[4][4] = {};
    float accs[4][4] = {};

    const int ktiles = (K + BK - 1) / BK;
    for (int kt = 0; kt < ktiles; ++kt) {
        const int kbase = kt * BK;
        // ---- stage A tile (64 rows x 16 k), coalesced on k ----
        {
            const int kk = kbase + lk;
            const bool kok = (kk < K);
#pragma unroll
            for (int i = 0; i < 4; ++i) {
                const int m = lm + 16 * i;
                As[lk][m] = kok ? A[(size_t)(row0 + m) * lda + kk] : 0.0f;
            }
        }
        // ---- stage B tiles (16 k x 64 cols), coalesced on n ----
#pragma unroll
        for (int i = 0; i < 4; ++i) {
            const int kk = kbase + lkb + 4 * i;
            float wm = 0.0f, ws2 = 0.0f;
            if (kk < K) {
                const size_t off = (size_t)kk * N + col0 + ln;
                wm = Wm[off];
                const float s = Ws[off] * drop;
                ws2 = s * s;
            }
            Bm[lkb + 4 * i][ln] = wm;
            Bs[lkb + 4 * i][ln] = ws2;
        }
        __syncthreads();

#pragma unroll
        for (int k = 0; k < BK; ++k) {
            float a[4], asq[4], bm[4], bs[4];
#pragma unroll
            for (int i = 0; i < 4; ++i) { a[i] = As[k][ty * 4 + i]; asq[i] = a[i] * a[i]; }
#pragma unroll
            for (int j = 0; j < 4; ++j) { bm[j] = Bm[k][tx * 4 + j]; bs[j] = Bs[k][tx * 4 + j]; }
#pragma unroll
            for (int i = 0; i < 4; ++i)
#pragma unroll
                for (int j = 0; j < 4; ++j) {
                    accm[i][j] += a[i] * bm[j];
                    accs[i][j] += asq[i] * bs[j];
                }
        }
        __syncthreads();
    }

    // ---- epilogue ----
    if (eps != nullptr) {
#pragma unroll
        for (int i = 0; i < 4; ++i) {
            const int r = row0 + ty * 4 + i;
#pragma unroll
            for (int j = 0; j < 4; ++j) {
                const int c = col0 + tx * 4 + j;
                const float sg = sqrtf(accs[i][j] + 1e-12f);
                float v = accm[i][j] + sg * eps[(size_t)r * N + c];
                v = v > 0.0f ? v : 0.01f * v;
                out[(size_t)r * ldo + c] = v;
            }
        }
    } else {
#pragma unroll
        for (int i = 0; i < 4; ++i) {
            const int r = row0 + ty * 4 + i;
#pragma unroll
            for (int j = 0; j < 4; ++j) {
                const int c = col0 + tx * 4 + j;
                out[(size_t)r * N + c]  = accm[i][j];
                sgout[(size_t)r * N + c] = sqrtf(accs[i][j] + 1e-12f);
            }
        }
    }
}

// ---------------------------------------------------------------------------
// Layer-1 expansion: h1[s,b,:] = leaky(mu1[b,:] + sg1[b,:]*eps1[s,b,:]), ones col
// ---------------------------------------------------------------------------
__global__ __launch_bounds__(256)
void expand1(const float* __restrict__ mu1, const float* __restrict__ sg1,
             const float* __restrict__ eps1, float* __restrict__ h1)
{
    const int c = blockIdx.x * 256 + threadIdx.x;
    const int r = blockIdx.y;              // 0..M2-1, r = s*BATCH + b
    if (c >= HP) return;
    float v;
    if (c == HID) {
        v = 1.0f;
    } else {
        const int b = r & (BATCH - 1);
        const float e = eps1[(size_t)r * HID + c];
        v = mu1[(size_t)b * HID + c] + sg1[(size_t)b * HID + c] * e;
        v = v > 0.0f ? v : 0.01f * v;
    }
    h1[(size_t)r * HP + c] = v;
}

__global__ __launch_bounds__(256)
void set_ones(float* __restrict__ h)
{
    const int r = blockIdx.x * 256 + threadIdx.x;
    if (r < M2) h[(size_t)r * HP + HID] = 1.0f;
}

// ---------------------------------------------------------------------------
// Layer 4: per-wave row dot-products (N=10) + fused log_softmax
// ---------------------------------------------------------------------------
__global__ __launch_bounds__(256)
void layer4(const float* __restrict__ h3, const float* __restrict__ Wm,
            const float* __restrict__ Ws, const float* __restrict__ eps4,
            float* __restrict__ out)
{
    const int wave = (int)((blockIdx.x * 256 + threadIdx.x) >> 6);
    const int lane = threadIdx.x & 63;
    if (wave >= M2) return;

    const float* x = h3 + (size_t)wave * HP;
    float am[NC] = {}, as[NC] = {};

    for (int k = lane; k < HP; k += 64) {
        const float xv = x[k];
        const float xs = xv * xv;
#pragma unroll
        for (int c = 0; c < NC; ++c) {
            am[c] += xv * Wm[k * NC + c];
            const float s = Ws[k * NC + c];
            as[c] += xs * s * s;
        }
    }
#pragma unroll
    for (int off = 32; off; off >>= 1) {
#pragma unroll
        for (int c = 0; c < NC; ++c) {
            am[c] += __shfl_xor(am[c], off, 64);
            as[c] += __shfl_xor(as[c], off, 64);
        }
    }
    if (lane == 0) {
        float logit[NC];
        float mx = -1e30f;
#pragma unroll
        for (int c = 0; c < NC; ++c) {
            const float sg = sqrtf(as[c] + 1e-12f);
            logit[c] = am[c] + sg * eps4[(size_t)wave * NC + c];
            mx = fmaxf(mx, logit[c]);
        }
        float sum = 0.0f;
#pragma unroll
        for (int c = 0; c < NC; ++c) sum += expf(logit[c] - mx);
        const float lse = mx + logf(sum);
#pragma unroll
        for (int c = 0; c < NC; ++c) out[(size_t)wave * NC + c] = logit[c] - lse;
    }
}

// ---------------------------------------------------------------------------
extern "C" void kernel_launch(void* const* d_in, const int* in_sizes, int n_in,
                              void* d_out, int out_size, void* d_ws, size_t ws_size,
                              hipStream_t stream)
{
    const float* inputs   = (const float*)d_in[0];
    const float* a1_mean  = (const float*)d_in[1];
    const float* a1_scale = (const float*)d_in[2];
    const float* a1_drop  = (const float*)d_in[3];
    const float* a2_mean  = (const float*)d_in[4];
    const float* a2_scale = (const float*)d_in[5];
    const float* a2_drop  = (const float*)d_in[6];
    const float* a3_mean  = (const float*)d_in[7];
    const float* a3_scale = (const float*)d_in[8];
    const float* a3_drop  = (const float*)d_in[9];
    const float* a4_mean  = (const float*)d_in[10];
    const float* a4_scale = (const float*)d_in[11];
    const float* eps1     = (const float*)d_in[12];
    const float* eps2     = (const float*)d_in[13];
    const float* eps3     = (const float*)d_in[14];
    const float* eps4     = (const float*)d_in[15];
    float* out = (float*)d_out;

    float* ws = (float*)d_ws;
    const size_t hsz = (size_t)M2 * HP;          // 10,506,240 floats
    float* h_a = ws;
    float* h_b = ws + hsz;
    float* mu1 = ws + 2 * hsz;
    float* sg1 = mu1 + (size_t)BATCH * HID;

    // ones column of h_b (disjoint from GEMM writes; h_a's comes from expand1)
    set_ones<<<(M2 + 255) / 256, 256, 0, stream>>>(h_b);

    // Layer 1 (sample-shared): mu1/sg1 [2048 x 512]
    {
        dim3 grid(HID / 64, BATCH / 64);
        dual_gemm64<<<grid, 256, 0, stream>>>(inputs, DIN, a1_mean, a1_scale,
                                              a1_drop, BATCH, HID, DIN,
                                              nullptr, mu1, HID, sg1);
    }
    // expand to h1 [20480 x 513]
    {
        dim3 grid((HP + 255) / 256, M2);
        expand1<<<grid, 256, 0, stream>>>(mu1, sg1, eps1, h_a);
    }
    // Layer 2 fused: h2 = leaky(mu + sg*eps2), [20480 x 513] -> h_b
    {
        dim3 grid(HID / 64, M2 / 64);
        dual_gemm64<<<grid, 256, 0, stream>>>(h_a, HP, a2_mean, a2_scale,
                                              a2_drop, M2, HID, HP,
                                              eps2, h_b, HP, nullptr);
    }
    // Layer 3 fused -> h_a (ones col survives from expand1)
    {
        dim3 grid(HID / 64, M2 / 64);
        dual_gemm64<<<grid, 256, 0, stream>>>(h_b, HP, a3_mean, a3_scale,
                                              a3_drop, M2, HID, HP,
                                              eps3, h_a, HP, nullptr);
    }
    // Layer 4 + log_softmax -> out [20480 x 10]
    layer4<<<(M2 * 64 + 255) / 256, 256, 0, stream>>>(h_a, a4_mean, a4_scale,
                                                      eps4, out);
}

// Round 2
// 454.759 us; speedup vs baseline: 2.7574x; 2.7574x over previous
//
#include <hip/hip_runtime.h>
#include <math.h>

#define BATCH 2048
#define DIN   784
#define HID   512
#define NC    10
#define NS    10

constexpr int HP  = HID + 1;        // 513
constexpr int M2  = NS * BATCH;     // 20480
constexpr int KP2 = 544;            // 513 padded to 17*32
constexpr int KP1 = 800;            // 784 padded to 25*32
constexpr int HROW = 544;           // padded h row length (bf16)

typedef __attribute__((ext_vector_type(8))) short          short8;
typedef __attribute__((ext_vector_type(8))) unsigned short ushort8;
typedef __attribute__((ext_vector_type(4))) float          floatx4;

__device__ inline unsigned short f2bf(float f) {
    unsigned u = __builtin_bit_cast(unsigned, f);
    u += 0x7FFFu + ((u >> 16) & 1u);
    return (unsigned short)(u >> 16);
}
__device__ inline float bf2f(unsigned short u) {
    return __builtin_bit_cast(float, (unsigned)u << 16);
}

// square each of 8 bf16 lanes (truncating repack; values are >= 0)
__device__ inline short8 sq8(short8 a) {
    union { short8 s; unsigned u[4]; } x;
    x.s = a;
#pragma unroll
    for (int i = 0; i < 4; ++i) {
        unsigned t = x.u[i];
        float lo = __builtin_bit_cast(float, t << 16);
        float hi = __builtin_bit_cast(float, t & 0xFFFF0000u);
        unsigned lq = __builtin_bit_cast(unsigned, lo * lo);
        unsigned hq = __builtin_bit_cast(unsigned, hi * hi);
        x.u[i] = (lq >> 16) | (hq & 0xFFFF0000u);
    }
    return x.s;
}

#define GLOAD_LDS16(g, l)                                                      \
    __builtin_amdgcn_global_load_lds(                                          \
        (const __attribute__((address_space(1))) void*)(g),                    \
        (__attribute__((address_space(3))) void*)(l), 16, 0, 0)

// ---------------------------------------------------------------------------
// Dual MFMA GEMM: accm = A@Wm, accs = (A.*A)@Ws2  (A bf16 [M x Kp], weights
// pre-transposed bf16 [512 x Kp]). Block tile 128x128, BK=32, 4 waves 64x64.
// eps != null: hout[R*544+C] = bf16(leaky(accm + sqrt(accs+1e-12)*eps[R*512+C]))
// eps == null: mu_out/sg_out f32 [M x 512]
// ---------------------------------------------------------------------------
__global__ __launch_bounds__(256)
void dual_gemm_mfma(const unsigned short* __restrict__ A,
                    const unsigned short* __restrict__ WTm,
                    const unsigned short* __restrict__ WTs2,
                    int Kp,
                    const float* __restrict__ eps,
                    unsigned short* __restrict__ hout,
                    float* __restrict__ mu_out,
                    float* __restrict__ sg_out)
{
    __shared__ __align__(16) char smem[24576];
    char* sA  = smem;
    char* sBm = smem + 8192;
    char* sBs = smem + 16384;

    const int tid  = threadIdx.x;
    const int lane = tid & 63;
    const int w    = tid >> 6;
    const int wm   = w & 1;          // wave m-half
    const int wn   = w >> 1;         // wave n-half
    const int quad = lane >> 4;
    const int l16  = lane & 15;

    const int row0 = blockIdx.y * 128;
    const int col0 = blockIdx.x * 128;

    floatx4 accm[4][4] = {};
    floatx4 accs[4][4] = {};

    const size_t KpB = (size_t)Kp * 2;
    const char* gA  = (const char*)(A   + (size_t)row0 * Kp);
    const char* gBm = (const char*)(WTm + (size_t)col0 * Kp);
    const char* gBs = (const char*)(WTs2 + (size_t)col0 * Kp);

    const int c0 = tid, r0c = c0 >> 2, s0c = c0 & 3;
    const int c1 = tid + 256, r1c = c1 >> 2, s1c = c1 & 3;

    const int ktiles = Kp >> 5;
    for (int kt = 0; kt < ktiles; ++kt) {
        const size_t kb = (size_t)kt * 64;   // 32 bf16 = 64 B
        {
            size_t go = (size_t)r0c * KpB + kb + s0c * 16;
            int lo = c0 * 16;
            GLOAD_LDS16(gA  + go, sA  + lo);
            GLOAD_LDS16(gBm + go, sBm + lo);
            GLOAD_LDS16(gBs + go, sBs + lo);
            go = (size_t)r1c * KpB + kb + s1c * 16;
            lo = c1 * 16;
            GLOAD_LDS16(gA  + go, sA  + lo);
            GLOAD_LDS16(gBm + go, sBm + lo);
            GLOAD_LDS16(gBs + go, sBs + lo);
        }
        __syncthreads();

        short8 aF[4], qF[4];
#pragma unroll
        for (int i = 0; i < 4; ++i) {
            const int off = ((wm * 64 + i * 16 + l16) * 32 + quad * 8) * 2;
            aF[i] = *(const short8*)(sA + off);
            qF[i] = sq8(aF[i]);
        }
#pragma unroll
        for (int j = 0; j < 4; ++j) {
            const int off = ((wn * 64 + j * 16 + l16) * 32 + quad * 8) * 2;
            short8 bm = *(const short8*)(sBm + off);
            short8 bs = *(const short8*)(sBs + off);
#pragma unroll
            for (int i = 0; i < 4; ++i) {
                accm[i][j] = __builtin_amdgcn_mfma_f32_16x16x32_bf16(aF[i], bm, accm[i][j], 0, 0, 0);
                accs[i][j] = __builtin_amdgcn_mfma_f32_16x16x32_bf16(qF[i], bs, accs[i][j], 0, 0, 0);
            }
        }
        __syncthreads();
    }

    // epilogue: C/D layout col=lane&15, row=quad*4+reg
    const int rbase = row0 + wm * 64 + quad * 4;
    const int cbase = col0 + wn * 64 + l16;
    if (eps != nullptr) {
#pragma unroll
        for (int i = 0; i < 4; ++i) {
#pragma unroll
            for (int r = 0; r < 4; ++r) {
                const int R = rbase + i * 16 + r;
#pragma unroll
                for (int j = 0; j < 4; ++j) {
                    const int C = cbase + j * 16;
                    const float sg = sqrtf(accs[i][j][r] + 1e-12f);
                    float v = accm[i][j][r] + sg * eps[(size_t)R * HID + C];
                    v = v > 0.0f ? v : 0.01f * v;
                    hout[(size_t)R * HROW + C] = f2bf(v);
                }
            }
        }
    } else {
#pragma unroll
        for (int i = 0; i < 4; ++i) {
#pragma unroll
            for (int r = 0; r < 4; ++r) {
                const int R = rbase + i * 16 + r;
#pragma unroll
                for (int j = 0; j < 4; ++j) {
                    const int C = cbase + j * 16;
                    mu_out[(size_t)R * HID + C] = accm[i][j][r];
                    sg_out[(size_t)R * HID + C] = sqrtf(accs[i][j][r] + 1e-12f);
                }
            }
        }
    }
}

// ---------------------------------------------------------------------------
// Weight pack: WTm[n][k] = bf16(Wm[k][n]); WTs2[n][k] = bf16((drop*Ws[k][n])^2)
// k >= K zero-padded to Kp. 32x32 LDS transpose tiles.
// ---------------------------------------------------------------------------
__global__ __launch_bounds__(256)
void pack_wT(const float* __restrict__ Wm, const float* __restrict__ Ws,
             const float* __restrict__ dropPtr, int K, int Kp,
             unsigned short* __restrict__ WTm, unsigned short* __restrict__ WTs2)
{
    __shared__ float tm[32][33];
    __shared__ float ts[32][33];
    const float drop = dropPtr[0];
    const int k0 = blockIdx.x * 32, n0 = blockIdx.y * 32;
    const int tx = threadIdx.x, ty = threadIdx.y;   // 32 x 8
#pragma unroll
    for (int i = 0; i < 4; ++i) {
        const int k = k0 + ty + 8 * i;
        float m = 0.0f, s2 = 0.0f;
        if (k < K) {
            m = Wm[(size_t)k * HID + n0 + tx];
            const float s = Ws[(size_t)k * HID + n0 + tx] * drop;
            s2 = s * s;
        }
        tm[ty + 8 * i][tx] = m;
        ts[ty + 8 * i][tx] = s2;
    }
    __syncthreads();
#pragma unroll
    for (int i = 0; i < 4; ++i) {
        const int n = n0 + ty + 8 * i;
        WTm[(size_t)n * Kp + k0 + tx]  = f2bf(tm[tx][ty + 8 * i]);
        WTs2[(size_t)n * Kp + k0 + tx] = f2bf(ts[tx][ty + 8 * i]);
    }
}

// convert inputs f32 [2048 x 784] -> bf16 [2048 x 800] zero-padded
__global__ __launch_bounds__(256)
void convert_x(const float* __restrict__ x, unsigned short* __restrict__ xb)
{
    const int idx = blockIdx.x * 256 + threadIdx.x;   // 2048*100
    if (idx >= BATCH * 100) return;
    const int r = idx / 100;
    const int c8 = (idx - r * 100) * 8;
    ushort8 o;
    if (c8 < DIN) {   // DIN=784=98*8, segs 0..97 fully in-range
        const floatx4 a = *(const floatx4*)(x + (size_t)r * DIN + c8);
        const floatx4 b = *(const floatx4*)(x + (size_t)r * DIN + c8 + 4);
#pragma unroll
        for (int j = 0; j < 4; ++j) { o[j] = f2bf(a[j]); o[4 + j] = f2bf(b[j]); }
    } else {
#pragma unroll
        for (int j = 0; j < 8; ++j) o[j] = 0;
    }
    *(ushort8*)(xb + (size_t)r * KP1 + c8) = o;
}

// h1[r][c] = bf16(leaky(mu1[b][c] + sg1[b][c]*eps1[r][c])), full 544-row incl pad
__global__ __launch_bounds__(256)
void expand1(const float* __restrict__ mu1, const float* __restrict__ sg1,
             const float* __restrict__ eps1, unsigned short* __restrict__ h1)
{
    const int idx = blockIdx.x * 256 + threadIdx.x;   // M2*68
    if (idx >= M2 * 68) return;
    const int r  = idx / 68;
    const int c8 = (idx - r * 68) * 8;
    ushort8 o;
    if (c8 < HID) {
        const int b = r & (BATCH - 1);
        const floatx4* ep = (const floatx4*)(eps1 + (size_t)r * HID + c8);
        const floatx4* mp = (const floatx4*)(mu1 + (size_t)b * HID + c8);
        const floatx4* sp = (const floatx4*)(sg1 + (size_t)b * HID + c8);
        const floatx4 e0 = ep[0], e1 = ep[1];
        const floatx4 m0 = mp[0], m1 = mp[1];
        const floatx4 s0 = sp[0], s1 = sp[1];
#pragma unroll
        for (int j = 0; j < 4; ++j) {
            float v = m0[j] + s0[j] * e0[j];
            v = v > 0.0f ? v : 0.01f * v;
            o[j] = f2bf(v);
            float u = m1[j] + s1[j] * e1[j];
            u = u > 0.0f ? u : 0.01f * u;
            o[4 + j] = f2bf(u);
        }
    } else {
#pragma unroll
        for (int j = 0; j < 8; ++j) o[j] = 0;
        if (c8 == HID) o[0] = 0x3F80;   // bf16(1.0) ones column
    }
    *(ushort8*)(h1 + (size_t)r * HROW + c8) = o;
}

// pad columns 512..543 of an h buffer (ones col + zeros)
__global__ __launch_bounds__(256)
void pad_h(unsigned short* __restrict__ h)
{
    const int idx = blockIdx.x * 256 + threadIdx.x;   // M2*4
    if (idx >= M2 * 4) return;
    const int r = idx >> 2, seg = idx & 3;
    ushort8 o;
#pragma unroll
    for (int j = 0; j < 8; ++j) o[j] = 0;
    if (seg == 0) o[0] = 0x3F80;
    *(ushort8*)(h + (size_t)r * HROW + HID + seg * 8) = o;
}

// Layer 4: per-wave dot products (N=10) + fused log_softmax; h3 is bf16 [M2 x 544]
__global__ __launch_bounds__(256)
void layer4(const unsigned short* __restrict__ h3, const float* __restrict__ Wm,
            const float* __restrict__ Ws, const float* __restrict__ eps4,
            float* __restrict__ out)
{
    const int wave = (int)((blockIdx.x * 256 + threadIdx.x) >> 6);
    const int lane = threadIdx.x & 63;
    if (wave >= M2) return;

    const unsigned short* x = h3 + (size_t)wave * HROW;
    float am[NC] = {}, as[NC] = {};
    for (int k = lane; k < HP; k += 64) {
        const float xv = bf2f(x[k]);
        const float xs = xv * xv;
#pragma unroll
        for (int c = 0; c < NC; ++c) {
            am[c] = fmaf(xv, Wm[k * NC + c], am[c]);
            const float s = Ws[k * NC + c];
            as[c] = fmaf(xs, s * s, as[c]);
        }
    }
#pragma unroll
    for (int off = 32; off; off >>= 1) {
#pragma unroll
        for (int c = 0; c < NC; ++c) {
            am[c] += __shfl_xor(am[c], off, 64);
            as[c] += __shfl_xor(as[c], off, 64);
        }
    }
    if (lane == 0) {
        float logit[NC];
        float mx = -1e30f;
#pragma unroll
        for (int c = 0; c < NC; ++c) {
            const float sg = sqrtf(as[c] + 1e-12f);
            logit[c] = am[c] + sg * eps4[(size_t)wave * NC + c];
            mx = fmaxf(mx, logit[c]);
        }
        float sum = 0.0f;
#pragma unroll
        for (int c = 0; c < NC; ++c) sum += expf(logit[c] - mx);
        const float lse = mx + logf(sum);
#pragma unroll
        for (int c = 0; c < NC; ++c) out[(size_t)wave * NC + c] = logit[c] - lse;
    }
}

// ---------------------------------------------------------------------------
extern "C" void kernel_launch(void* const* d_in, const int* in_sizes, int n_in,
                              void* d_out, int out_size, void* d_ws, size_t ws_size,
                              hipStream_t stream)
{
    const float* inputs   = (const float*)d_in[0];
    const float* a1_mean  = (const float*)d_in[1];
    const float* a1_scale = (const float*)d_in[2];
    const float* a1_drop  = (const float*)d_in[3];
    const float* a2_mean  = (const float*)d_in[4];
    const float* a2_scale = (const float*)d_in[5];
    const float* a2_drop  = (const float*)d_in[6];
    const float* a3_mean  = (const float*)d_in[7];
    const float* a3_scale = (const float*)d_in[8];
    const float* a3_drop  = (const float*)d_in[9];
    const float* a4_mean  = (const float*)d_in[10];
    const float* a4_scale = (const float*)d_in[11];
    const float* eps1     = (const float*)d_in[12];
    const float* eps2     = (const float*)d_in[13];
    const float* eps3     = (const float*)d_in[14];
    const float* eps4     = (const float*)d_in[15];
    float* out = (float*)d_out;

    char* p = (char*)d_ws;
    unsigned short* h_a  = (unsigned short*)p; p += (size_t)M2 * HROW * 2;
    unsigned short* h_b  = (unsigned short*)p; p += (size_t)M2 * HROW * 2;
    unsigned short* xb   = (unsigned short*)p; p += (size_t)BATCH * KP1 * 2;
    unsigned short* WT1m = (unsigned short*)p; p += (size_t)HID * KP1 * 2;
    unsigned short* WT1s = (unsigned short*)p; p += (size_t)HID * KP1 * 2;
    unsigned short* WT2m = (unsigned short*)p; p += (size_t)HID * KP2 * 2;
    unsigned short* WT2s = (unsigned short*)p; p += (size_t)HID * KP2 * 2;
    unsigned short* WT3m = (unsigned short*)p; p += (size_t)HID * KP2 * 2;
    unsigned short* WT3s = (unsigned short*)p; p += (size_t)HID * KP2 * 2;
    float* mu1 = (float*)p; p += (size_t)BATCH * HID * 4;
    float* sg1 = (float*)p; p += (size_t)BATCH * HID * 4;

    // pack / convert
    convert_x<<<(BATCH * 100 + 255) / 256, 256, 0, stream>>>(inputs, xb);
    pack_wT<<<dim3(KP1 / 32, HID / 32), dim3(32, 8), 0, stream>>>(a1_mean, a1_scale, a1_drop, DIN, KP1, WT1m, WT1s);
    pack_wT<<<dim3(KP2 / 32, HID / 32), dim3(32, 8), 0, stream>>>(a2_mean, a2_scale, a2_drop, HP, KP2, WT2m, WT2s);
    pack_wT<<<dim3(KP2 / 32, HID / 32), dim3(32, 8), 0, stream>>>(a3_mean, a3_scale, a3_drop, HP, KP2, WT3m, WT3s);
    pad_h<<<(M2 * 4 + 255) / 256, 256, 0, stream>>>(h_b);

    // layer 1 (sample-shared): mu1/sg1 [2048 x 512]
    dual_gemm_mfma<<<dim3(HID / 128, BATCH / 128), 256, 0, stream>>>(
        xb, WT1m, WT1s, KP1, nullptr, nullptr, mu1, sg1);

    // expand to h1 [20480 x 544] (incl ones + zero pad)
    expand1<<<(M2 * 68 + 255) / 256, 256, 0, stream>>>(mu1, sg1, eps1, h_a);

    // layer 2 fused -> h_b
    dual_gemm_mfma<<<dim3(HID / 128, M2 / 128), 256, 0, stream>>>(
        h_a, WT2m, WT2s, KP2, eps2, h_b, nullptr, nullptr);

    // layer 3 fused -> h_a (pad cols survive from expand1)
    dual_gemm_mfma<<<dim3(HID / 128, M2 / 128), 256, 0, stream>>>(
        h_b, WT3m, WT3s, KP2, eps3, h_a, nullptr, nullptr);

    // layer 4 + log_softmax
    layer4<<<(M2 * 64 + 255) / 256, 256, 0, stream>>>(h_a, a4_mean, a4_scale, eps4, out);
}

// Round 3
// 444.015 us; speedup vs baseline: 2.8241x; 1.0242x over previous
//
#include <hip/hip_runtime.h>
#include <math.h>

#define BATCH 2048
#define DIN   784
#define HID   512
#define NC    10
#define NS    10

constexpr int HP  = HID + 1;        // 513
constexpr int M2  = NS * BATCH;     // 20480
constexpr int KP2 = 544;            // 513 padded to 17*32
constexpr int KP1 = 800;            // 784 padded to 25*32
constexpr int HROW = 544;           // padded h row length (bf16)

typedef __attribute__((ext_vector_type(8))) short          short8;
typedef __attribute__((ext_vector_type(8))) unsigned short ushort8;
typedef __attribute__((ext_vector_type(4))) float          floatx4;

__device__ inline unsigned short f2bf(float f) {
    unsigned u = __builtin_bit_cast(unsigned, f);
    u += 0x7FFFu + ((u >> 16) & 1u);
    return (unsigned short)(u >> 16);
}
__device__ inline float bf2f(unsigned short u) {
    return __builtin_bit_cast(float, (unsigned)u << 16);
}

// square each of 8 bf16 lanes (truncating repack; values are >= 0)
__device__ inline short8 sq8(short8 a) {
    union { short8 s; unsigned u[4]; } x;
    x.s = a;
#pragma unroll
    for (int i = 0; i < 4; ++i) {
        unsigned t = x.u[i];
        float lo = __builtin_bit_cast(float, t << 16);
        float hi = __builtin_bit_cast(float, t & 0xFFFF0000u);
        unsigned lq = __builtin_bit_cast(unsigned, lo * lo);
        unsigned hq = __builtin_bit_cast(unsigned, hi * hi);
        x.u[i] = (lq >> 16) | (hq & 0xFFFF0000u);
    }
    return x.s;
}

#define GLOAD_LDS16(g, l)                                                      \
    __builtin_amdgcn_global_load_lds(                                          \
        (const __attribute__((address_space(1))) void*)(g),                    \
        (__attribute__((address_space(3))) void*)(l), 16, 0, 0)

// ---------------------------------------------------------------------------
// Dual MFMA GEMM: accm = A@Wm, accs = (A.*A)@Ws2  (A bf16 [M x Kp], weights
// pre-transposed bf16 [512 x Kp]). Block tile 64(M)x128(N), 2 waves (64x64).
// eps tile is prefetched into LDS across the K loop (overlaps compute).
// eps != null: hout[R*544+C] = bf16(leaky(accm + sqrt(accs+1e-12)*eps[R*512+C]))
// eps == null: mu_out/sg_out f32 [M x 512]
// ---------------------------------------------------------------------------
__global__ __launch_bounds__(128)
void dual_gemm_mfma(const unsigned short* __restrict__ A,
                    const unsigned short* __restrict__ WTm,
                    const unsigned short* __restrict__ WTs2,
                    int Kp,
                    const float* __restrict__ eps,
                    unsigned short* __restrict__ hout,
                    float* __restrict__ mu_out,
                    float* __restrict__ sg_out)
{
    // 4K A + 8K Bm + 8K Bs + 32K eps = 53248 B -> 3 blocks/CU
    __shared__ __align__(16) char smem[53248];
    char*  sA   = smem;
    char*  sBm  = smem + 4096;
    char*  sBs  = smem + 12288;
    float* epsL = (float*)(smem + 20480);

    const int tid  = threadIdx.x;        // 0..127
    const int lane = tid & 63;
    const int w    = tid >> 6;           // wave 0/1 -> n-half
    const int quad = lane >> 4;
    const int l16  = lane & 15;

    const int row0 = blockIdx.y * 64;
    const int col0 = blockIdx.x * 128;

    floatx4 accm[4][4] = {};
    floatx4 accs[4][4] = {};

    const size_t KpB = (size_t)Kp * 2;
    const char* gA  = (const char*)(A    + (size_t)row0 * Kp);
    const char* gBm = (const char*)(WTm  + (size_t)col0 * Kp);
    const char* gBs = (const char*)(WTs2 + (size_t)col0 * Kp);
    const float* gE = eps ? (eps + (size_t)row0 * HID + col0) : nullptr;

    const int ktiles = Kp >> 5;
    for (int kt = 0; kt < ktiles; ++kt) {
        const size_t kb = (size_t)kt * 64;   // 32 bf16 = 64 B
        // ---- A tile: 64 rows x 32 k = 4 KB = 256 x 16B chunks ----
#pragma unroll
        for (int i = 0; i < 2; ++i) {
            const int c = tid + 128 * i;
            const int r = c >> 2, s = c & 3;
            GLOAD_LDS16(gA + (size_t)r * KpB + kb + s * 16, sA + c * 16);
        }
        // ---- B tiles: 128 n x 32 k = 8 KB each ----
#pragma unroll
        for (int i = 0; i < 4; ++i) {
            const int c = tid + 128 * i;
            const int r = c >> 2, s = c & 3;
            const size_t go = (size_t)r * KpB + kb + s * 16;
            GLOAD_LDS16(gBm + go, sBm + c * 16);
            GLOAD_LDS16(gBs + go, sBs + c * 16);
        }
        // ---- eps prefetch: 2 KB per ktile across first 16 ktiles ----
        if (gE != nullptr && kt < 16) {
            const int e = kt * 512 + tid * 4;       // f32 element in 64x128 tile
            const int r = e >> 7, cc = e & 127;
            GLOAD_LDS16(gE + (size_t)r * HID + cc, (char*)epsL + (size_t)e * 4);
        }
        __syncthreads();

        short8 aF[4], qF[4];
#pragma unroll
        for (int i = 0; i < 4; ++i) {
            const int off = ((i * 16 + l16) * 32 + quad * 8) * 2;
            aF[i] = *(const short8*)(sA + off);
            qF[i] = sq8(aF[i]);
        }
#pragma unroll
        for (int j = 0; j < 4; ++j) {
            const int off = ((w * 64 + j * 16 + l16) * 32 + quad * 8) * 2;
            short8 bm = *(const short8*)(sBm + off);
            short8 bs = *(const short8*)(sBs + off);
#pragma unroll
            for (int i = 0; i < 4; ++i) {
                accm[i][j] = __builtin_amdgcn_mfma_f32_16x16x32_bf16(aF[i], bm, accm[i][j], 0, 0, 0);
                accs[i][j] = __builtin_amdgcn_mfma_f32_16x16x32_bf16(qF[i], bs, accs[i][j], 0, 0, 0);
            }
        }
        __syncthreads();
    }

    // epilogue: C/D layout col=lane&15, row=quad*4+reg
    if (eps != nullptr) {
#pragma unroll
        for (int i = 0; i < 4; ++i) {
#pragma unroll
            for (int r = 0; r < 4; ++r) {
                const int rl = i * 16 + quad * 4 + r;
                const int R  = row0 + rl;
#pragma unroll
                for (int j = 0; j < 4; ++j) {
                    const int cl = w * 64 + j * 16 + l16;
                    const float sg = sqrtf(accs[i][j][r] + 1e-12f);
                    float v = accm[i][j][r] + sg * epsL[rl * 128 + cl];
                    v = v > 0.0f ? v : 0.01f * v;
                    hout[(size_t)R * HROW + col0 + cl] = f2bf(v);
                }
            }
        }
    } else {
#pragma unroll
        for (int i = 0; i < 4; ++i) {
#pragma unroll
            for (int r = 0; r < 4; ++r) {
                const int R = row0 + i * 16 + quad * 4 + r;
#pragma unroll
                for (int j = 0; j < 4; ++j) {
                    const int C = col0 + w * 64 + j * 16 + l16;
                    mu_out[(size_t)R * HID + C] = accm[i][j][r];
                    sg_out[(size_t)R * HID + C] = sqrtf(accs[i][j][r] + 1e-12f);
                }
            }
        }
    }
}

// ---------------------------------------------------------------------------
// Weight pack: WTm[n][k] = bf16(Wm[k][n]); WTs2[n][k] = bf16((drop*Ws[k][n])^2)
// ---------------------------------------------------------------------------
__global__ __launch_bounds__(256)
void pack_wT(const float* __restrict__ Wm, const float* __restrict__ Ws,
             const float* __restrict__ dropPtr, int K, int Kp,
             unsigned short* __restrict__ WTm, unsigned short* __restrict__ WTs2)
{
    __shared__ float tm[32][33];
    __shared__ float ts[32][33];
    const float drop = dropPtr[0];
    const int k0 = blockIdx.x * 32, n0 = blockIdx.y * 32;
    const int tx = threadIdx.x, ty = threadIdx.y;   // 32 x 8
#pragma unroll
    for (int i = 0; i < 4; ++i) {
        const int k = k0 + ty + 8 * i;
        float m = 0.0f, s2 = 0.0f;
        if (k < K) {
            m = Wm[(size_t)k * HID + n0 + tx];
            const float s = Ws[(size_t)k * HID + n0 + tx] * drop;
            s2 = s * s;
        }
        tm[ty + 8 * i][tx] = m;
        ts[ty + 8 * i][tx] = s2;
    }
    __syncthreads();
#pragma unroll
    for (int i = 0; i < 4; ++i) {
        const int n = n0 + ty + 8 * i;
        WTm[(size_t)n * Kp + k0 + tx]  = f2bf(tm[tx][ty + 8 * i]);
        WTs2[(size_t)n * Kp + k0 + tx] = f2bf(ts[tx][ty + 8 * i]);
    }
}

// convert inputs f32 [2048 x 784] -> bf16 [2048 x 800] zero-padded
__global__ __launch_bounds__(256)
void convert_x(const float* __restrict__ x, unsigned short* __restrict__ xb)
{
    const int idx = blockIdx.x * 256 + threadIdx.x;   // 2048*100
    if (idx >= BATCH * 100) return;
    const int r = idx / 100;
    const int c8 = (idx - r * 100) * 8;
    ushort8 o;
    if (c8 < DIN) {   // DIN=784=98*8
        const floatx4 a = *(const floatx4*)(x + (size_t)r * DIN + c8);
        const floatx4 b = *(const floatx4*)(x + (size_t)r * DIN + c8 + 4);
#pragma unroll
        for (int j = 0; j < 4; ++j) { o[j] = f2bf(a[j]); o[4 + j] = f2bf(b[j]); }
    } else {
#pragma unroll
        for (int j = 0; j < 8; ++j) o[j] = 0;
    }
    *(ushort8*)(xb + (size_t)r * KP1 + c8) = o;
}

// h1[r][c] = bf16(leaky(mu1[b][c] + sg1[b][c]*eps1[r][c])), full 544-row incl pad
__global__ __launch_bounds__(256)
void expand1(const float* __restrict__ mu1, const float* __restrict__ sg1,
             const float* __restrict__ eps1, unsigned short* __restrict__ h1)
{
    const int idx = blockIdx.x * 256 + threadIdx.x;   // M2*68
    if (idx >= M2 * 68) return;
    const int r  = idx / 68;
    const int c8 = (idx - r * 68) * 8;
    ushort8 o;
    if (c8 < HID) {
        const int b = r & (BATCH - 1);
        const floatx4* ep = (const floatx4*)(eps1 + (size_t)r * HID + c8);
        const floatx4* mp = (const floatx4*)(mu1 + (size_t)b * HID + c8);
        const floatx4* sp = (const floatx4*)(sg1 + (size_t)b * HID + c8);
        const floatx4 e0 = ep[0], e1 = ep[1];
        const floatx4 m0 = mp[0], m1 = mp[1];
        const floatx4 s0 = sp[0], s1 = sp[1];
#pragma unroll
        for (int j = 0; j < 4; ++j) {
            float v = m0[j] + s0[j] * e0[j];
            v = v > 0.0f ? v : 0.01f * v;
            o[j] = f2bf(v);
            float u = m1[j] + s1[j] * e1[j];
            u = u > 0.0f ? u : 0.01f * u;
            o[4 + j] = f2bf(u);
        }
    } else {
#pragma unroll
        for (int j = 0; j < 8; ++j) o[j] = 0;
        if (c8 == HID) o[0] = 0x3F80;   // bf16(1.0) ones column
    }
    *(ushort8*)(h1 + (size_t)r * HROW + c8) = o;
}

// pad columns 512..543 of an h buffer (ones col + zeros)
__global__ __launch_bounds__(256)
void pad_h(unsigned short* __restrict__ h)
{
    const int idx = blockIdx.x * 256 + threadIdx.x;   // M2*4
    if (idx >= M2 * 4) return;
    const int r = idx >> 2, seg = idx & 3;
    ushort8 o;
#pragma unroll
    for (int j = 0; j < 8; ++j) o[j] = 0;
    if (seg == 0) o[0] = 0x3F80;
    *(ushort8*)(h + (size_t)r * HROW + HID + seg * 8) = o;
}

// Layer 4: per-wave dot products (N=10) + fused log_softmax; h3 is bf16 [M2 x 544]
__global__ __launch_bounds__(256)
void layer4(const unsigned short* __restrict__ h3, const float* __restrict__ Wm,
            const float* __restrict__ Ws, const float* __restrict__ eps4,
            float* __restrict__ out)
{
    const int wave = (int)((blockIdx.x * 256 + threadIdx.x) >> 6);
    const int lane = threadIdx.x & 63;
    if (wave >= M2) return;

    const unsigned short* x = h3 + (size_t)wave * HROW;
    float am[NC] = {}, as[NC] = {};
    for (int k = lane; k < HP; k += 64) {
        const float xv = bf2f(x[k]);
        const float xs = xv * xv;
#pragma unroll
        for (int c = 0; c < NC; ++c) {
            am[c] = fmaf(xv, Wm[k * NC + c], am[c]);
            const float s = Ws[k * NC + c];
            as[c] = fmaf(xs, s * s, as[c]);
        }
    }
#pragma unroll
    for (int off = 32; off; off >>= 1) {
#pragma unroll
        for (int c = 0; c < NC; ++c) {
            am[c] += __shfl_xor(am[c], off, 64);
            as[c] += __shfl_xor(as[c], off, 64);
        }
    }
    if (lane == 0) {
        float logit[NC];
        float mx = -1e30f;
#pragma unroll
        for (int c = 0; c < NC; ++c) {
            const float sg = sqrtf(as[c] + 1e-12f);
            logit[c] = am[c] + sg * eps4[(size_t)wave * NC + c];
            mx = fmaxf(mx, logit[c]);
        }
        float sum = 0.0f;
#pragma unroll
        for (int c = 0; c < NC; ++c) sum += expf(logit[c] - mx);
        const float lse = mx + logf(sum);
#pragma unroll
        for (int c = 0; c < NC; ++c) out[(size_t)wave * NC + c] = logit[c] - lse;
    }
}

// ---------------------------------------------------------------------------
extern "C" void kernel_launch(void* const* d_in, const int* in_sizes, int n_in,
                              void* d_out, int out_size, void* d_ws, size_t ws_size,
                              hipStream_t stream)
{
    const float* inputs   = (const float*)d_in[0];
    const float* a1_mean  = (const float*)d_in[1];
    const float* a1_scale = (const float*)d_in[2];
    const float* a1_drop  = (const float*)d_in[3];
    const float* a2_mean  = (const float*)d_in[4];
    const float* a2_scale = (const float*)d_in[5];
    const float* a2_drop  = (const float*)d_in[6];
    const float* a3_mean  = (const float*)d_in[7];
    const float* a3_scale = (const float*)d_in[8];
    const float* a3_drop  = (const float*)d_in[9];
    const float* a4_mean  = (const float*)d_in[10];
    const float* a4_scale = (const float*)d_in[11];
    const float* eps1     = (const float*)d_in[12];
    const float* eps2     = (const float*)d_in[13];
    const float* eps3     = (const float*)d_in[14];
    const float* eps4     = (const float*)d_in[15];
    float* out = (float*)d_out;

    char* p = (char*)d_ws;
    unsigned short* h_a  = (unsigned short*)p; p += (size_t)M2 * HROW * 2;
    unsigned short* h_b  = (unsigned short*)p; p += (size_t)M2 * HROW * 2;
    unsigned short* xb   = (unsigned short*)p; p += (size_t)BATCH * KP1 * 2;
    unsigned short* WT1m = (unsigned short*)p; p += (size_t)HID * KP1 * 2;
    unsigned short* WT1s = (unsigned short*)p; p += (size_t)HID * KP1 * 2;
    unsigned short* WT2m = (unsigned short*)p; p += (size_t)HID * KP2 * 2;
    unsigned short* WT2s = (unsigned short*)p; p += (size_t)HID * KP2 * 2;
    unsigned short* WT3m = (unsigned short*)p; p += (size_t)HID * KP2 * 2;
    unsigned short* WT3s = (unsigned short*)p; p += (size_t)HID * KP2 * 2;
    float* mu1 = (float*)p; p += (size_t)BATCH * HID * 4;
    float* sg1 = (float*)p; p += (size_t)BATCH * HID * 4;

    // pack / convert
    convert_x<<<(BATCH * 100 + 255) / 256, 256, 0, stream>>>(inputs, xb);
    pack_wT<<<dim3(KP1 / 32, HID / 32), dim3(32, 8), 0, stream>>>(a1_mean, a1_scale, a1_drop, DIN, KP1, WT1m, WT1s);
    pack_wT<<<dim3(KP2 / 32, HID / 32), dim3(32, 8), 0, stream>>>(a2_mean, a2_scale, a2_drop, HP, KP2, WT2m, WT2s);
    pack_wT<<<dim3(KP2 / 32, HID / 32), dim3(32, 8), 0, stream>>>(a3_mean, a3_scale, a3_drop, HP, KP2, WT3m, WT3s);
    pad_h<<<(M2 * 4 + 255) / 256, 256, 0, stream>>>(h_b);

    // layer 1 (sample-shared): mu1/sg1 [2048 x 512]
    dual_gemm_mfma<<<dim3(HID / 128, BATCH / 64), 128, 0, stream>>>(
        xb, WT1m, WT1s, KP1, nullptr, nullptr, mu1, sg1);

    // expand to h1 [20480 x 544] (incl ones + zero pad)
    expand1<<<(M2 * 68 + 255) / 256, 256, 0, stream>>>(mu1, sg1, eps1, h_a);

    // layer 2 fused -> h_b
    dual_gemm_mfma<<<dim3(HID / 128, M2 / 64), 128, 0, stream>>>(
        h_a, WT2m, WT2s, KP2, eps2, h_b, nullptr, nullptr);

    // layer 3 fused -> h_a (pad cols survive from expand1)
    dual_gemm_mfma<<<dim3(HID / 128, M2 / 64), 128, 0, stream>>>(
        h_b, WT3m, WT3s, KP2, eps3, h_a, nullptr, nullptr);

    // layer 4 + log_softmax
    layer4<<<(M2 * 64 + 255) / 256, 256, 0, stream>>>(h_a, a4_mean, a4_scale, eps4, out);
}

// Round 4
// 395.426 us; speedup vs baseline: 3.1711x; 1.1229x over previous
//
#include <hip/hip_runtime.h>
#include <math.h>

#define BATCH 2048
#define DIN   784
#define HID   512
#define NC    10
#define NS    10

constexpr int HP  = HID + 1;        // 513
constexpr int M2  = NS * BATCH;     // 20480
constexpr int KP2 = 544;            // 513 padded to 17*32
constexpr int KP1 = 800;            // 784 padded to 25*32
constexpr int HROW = 544;           // padded h row length (bf16)

typedef __attribute__((ext_vector_type(8))) short          short8;
typedef __attribute__((ext_vector_type(8))) unsigned short ushort8;
typedef __attribute__((ext_vector_type(4))) float          floatx4;

__device__ inline unsigned short f2bf(float f) {
    unsigned u = __builtin_bit_cast(unsigned, f);
    u += 0x7FFFu + ((u >> 16) & 1u);
    return (unsigned short)(u >> 16);
}
__device__ inline float bf2f(unsigned short u) {
    return __builtin_bit_cast(float, (unsigned)u << 16);
}

// square each of 8 bf16 lanes (truncating repack; values are >= 0)
__device__ inline short8 sq8(short8 a) {
    union { short8 s; unsigned u[4]; } x;
    x.s = a;
#pragma unroll
    for (int i = 0; i < 4; ++i) {
        unsigned t = x.u[i];
        float lo = __builtin_bit_cast(float, t << 16);
        float hi = __builtin_bit_cast(float, t & 0xFFFF0000u);
        unsigned lq = __builtin_bit_cast(unsigned, lo * lo);
        unsigned hq = __builtin_bit_cast(unsigned, hi * hi);
        x.u[i] = (lq >> 16) | (hq & 0xFFFF0000u);
    }
    return x.s;
}

#define GLOAD_LDS16(g, l)                                                      \
    __builtin_amdgcn_global_load_lds(                                          \
        (const __attribute__((address_space(1))) void*)(g),                    \
        (__attribute__((address_space(3))) void*)(l), 16, 0, 0)

// ---------------------------------------------------------------------------
// Dual MFMA GEMM, double-buffered: accm = A@Wm, accs = (A.*A)@Ws2.
// A bf16 [M x Kp]; weights pre-transposed bf16 [512 x Kp].
// Block tile 64(M) x 64(N), 4 waves; wave w computes 64 rows x cols [16w,16w+16).
// K-loop: barrier FIRST (drains tile-kt loads issued one iteration earlier,
// which overlapped the previous compute), then issue kt+1 glds into the other
// buffer, then compute tile kt. eps tile (64x64 f32, 16 KB) DMA'd across loop.
// ---------------------------------------------------------------------------
__global__ __launch_bounds__(256)
void dual_gemm_mfma(const unsigned short* __restrict__ A,
                    const unsigned short* __restrict__ WTm,
                    const unsigned short* __restrict__ WTs2,
                    int Kp,
                    const float* __restrict__ eps,
                    unsigned short* __restrict__ hout,
                    float* __restrict__ mu_out,
                    float* __restrict__ sg_out)
{
    // buf0 12K | buf1 12K | eps 16K = 40 KB -> 4 blocks/CU
    __shared__ __align__(16) char smem[40960];
    float* epsL = (float*)(smem + 24576);

    const int tid  = threadIdx.x;        // 0..255
    const int lane = tid & 63;
    const int w    = tid >> 6;           // wave 0..3 -> 16-col slice
    const int quad = lane >> 4;
    const int l16  = lane & 15;

    const int row0 = blockIdx.y * 64;
    const int col0 = blockIdx.x * 64;

    const size_t KpB = (size_t)Kp * 2;
    const char* gA  = (const char*)(A    + (size_t)row0 * Kp);
    const char* gBm = (const char*)(WTm  + (size_t)col0 * Kp);
    const char* gBs = (const char*)(WTs2 + (size_t)col0 * Kp);
    const float* gE = eps ? (eps + (size_t)row0 * HID + col0) : nullptr;

    // per-thread staging chunk: 64 rows x 32 k bf16 = 4 KB = 256 x 16 B
    const int sr = tid >> 2, ss = tid & 3;
    auto stage = [&](int kt, char* buf) {
        const size_t go = (size_t)sr * KpB + (size_t)kt * 64 + ss * 16;
        GLOAD_LDS16(gA  + go, buf + tid * 16);
        GLOAD_LDS16(gBm + go, buf + 4096 + tid * 16);
        GLOAD_LDS16(gBs + go, buf + 8192 + tid * 16);
    };

    stage(0, smem);   // prologue into buf0

    floatx4 accm[4] = {};
    floatx4 accs[4] = {};

    const int ktiles = Kp >> 5;
    const int boffB = 4096 + ((w * 16 + l16) * 32 + quad * 8) * 2;
    for (int kt = 0; kt < ktiles; ++kt) {
        __syncthreads();   // drains tile-kt loads (issued last iter, overlapped)
        char* cur = smem + (kt & 1) * 12288;
        if (kt + 1 < ktiles) stage(kt + 1, smem + ((kt + 1) & 1) * 12288);
        if (gE != nullptr && kt < 16 && tid < 64) {
            const int c2 = kt * 64 + tid;               // 16B chunk of eps tile
            const int r = c2 >> 4, s = c2 & 15;
            GLOAD_LDS16(gE + (size_t)r * HID + s * 4, (char*)epsL + (size_t)c2 * 16);
        }
        // compute tile kt
        const short8 bm = *(const short8*)(cur + boffB);
        const short8 bs = *(const short8*)(cur + boffB + 4096);
#pragma unroll
        for (int i = 0; i < 4; ++i) {
            const short8 a = *(const short8*)(cur + ((i * 16 + l16) * 32 + quad * 8) * 2);
            const short8 q = sq8(a);
            accm[i] = __builtin_amdgcn_mfma_f32_16x16x32_bf16(a, bm, accm[i], 0, 0, 0);
            accs[i] = __builtin_amdgcn_mfma_f32_16x16x32_bf16(q, bs, accs[i], 0, 0, 0);
        }
    }

    // epilogue: C/D layout col=lane&15, row=quad*4+reg
    const int cl = w * 16 + l16;
    if (eps != nullptr) {
#pragma unroll
        for (int i = 0; i < 4; ++i) {
#pragma unroll
            for (int r = 0; r < 4; ++r) {
                const int rl = i * 16 + quad * 4 + r;
                const float sg = sqrtf(accs[i][r] + 1e-12f);
                float v = accm[i][r] + sg * epsL[rl * 64 + cl];
                v = v > 0.0f ? v : 0.01f * v;
                hout[(size_t)(row0 + rl) * HROW + col0 + cl] = f2bf(v);
            }
        }
    } else {
#pragma unroll
        for (int i = 0; i < 4; ++i) {
#pragma unroll
            for (int r = 0; r < 4; ++r) {
                const int rl = i * 16 + quad * 4 + r;
                const size_t o = (size_t)(row0 + rl) * HID + col0 + cl;
                mu_out[o] = accm[i][r];
                sg_out[o] = sqrtf(accs[i][r] + 1e-12f);
            }
        }
    }
}

// ---------------------------------------------------------------------------
// Weight pack: WTm[n][k] = bf16(Wm[k][n]); WTs2[n][k] = bf16((drop*Ws[k][n])^2)
// ---------------------------------------------------------------------------
__global__ __launch_bounds__(256)
void pack_wT(const float* __restrict__ Wm, const float* __restrict__ Ws,
             const float* __restrict__ dropPtr, int K, int Kp,
             unsigned short* __restrict__ WTm, unsigned short* __restrict__ WTs2)
{
    __shared__ float tm[32][33];
    __shared__ float ts[32][33];
    const float drop = dropPtr[0];
    const int k0 = blockIdx.x * 32, n0 = blockIdx.y * 32;
    const int tx = threadIdx.x, ty = threadIdx.y;   // 32 x 8
#pragma unroll
    for (int i = 0; i < 4; ++i) {
        const int k = k0 + ty + 8 * i;
        float m = 0.0f, s2 = 0.0f;
        if (k < K) {
            m = Wm[(size_t)k * HID + n0 + tx];
            const float s = Ws[(size_t)k * HID + n0 + tx] * drop;
            s2 = s * s;
        }
        tm[ty + 8 * i][tx] = m;
        ts[ty + 8 * i][tx] = s2;
    }
    __syncthreads();
#pragma unroll
    for (int i = 0; i < 4; ++i) {
        const int n = n0 + ty + 8 * i;
        WTm[(size_t)n * Kp + k0 + tx]  = f2bf(tm[tx][ty + 8 * i]);
        WTs2[(size_t)n * Kp + k0 + tx] = f2bf(ts[tx][ty + 8 * i]);
    }
}

// convert inputs f32 [2048 x 784] -> bf16 [2048 x 800] zero-padded
__global__ __launch_bounds__(256)
void convert_x(const float* __restrict__ x, unsigned short* __restrict__ xb)
{
    const int idx = blockIdx.x * 256 + threadIdx.x;   // 2048*100
    if (idx >= BATCH * 100) return;
    const int r = idx / 100;
    const int c8 = (idx - r * 100) * 8;
    ushort8 o;
    if (c8 < DIN) {   // DIN=784=98*8
        const floatx4 a = *(const floatx4*)(x + (size_t)r * DIN + c8);
        const floatx4 b = *(const floatx4*)(x + (size_t)r * DIN + c8 + 4);
#pragma unroll
        for (int j = 0; j < 4; ++j) { o[j] = f2bf(a[j]); o[4 + j] = f2bf(b[j]); }
    } else {
#pragma unroll
        for (int j = 0; j < 8; ++j) o[j] = 0;
    }
    *(ushort8*)(xb + (size_t)r * KP1 + c8) = o;
}

// h1[r][c] = bf16(leaky(mu1[b][c] + sg1[b][c]*eps1[r][c])), full 544-row incl pad
__global__ __launch_bounds__(256)
void expand1(const float* __restrict__ mu1, const float* __restrict__ sg1,
             const float* __restrict__ eps1, unsigned short* __restrict__ h1)
{
    const int idx = blockIdx.x * 256 + threadIdx.x;   // M2*68
    if (idx >= M2 * 68) return;
    const int r  = idx / 68;
    const int c8 = (idx - r * 68) * 8;
    ushort8 o;
    if (c8 < HID) {
        const int b = r & (BATCH - 1);
        const floatx4* ep = (const floatx4*)(eps1 + (size_t)r * HID + c8);
        const floatx4* mp = (const floatx4*)(mu1 + (size_t)b * HID + c8);
        const floatx4* sp = (const floatx4*)(sg1 + (size_t)b * HID + c8);
        const floatx4 e0 = ep[0], e1 = ep[1];
        const floatx4 m0 = mp[0], m1 = mp[1];
        const floatx4 s0 = sp[0], s1 = sp[1];
#pragma unroll
        for (int j = 0; j < 4; ++j) {
            float v = m0[j] + s0[j] * e0[j];
            v = v > 0.0f ? v : 0.01f * v;
            o[j] = f2bf(v);
            float u = m1[j] + s1[j] * e1[j];
            u = u > 0.0f ? u : 0.01f * u;
            o[4 + j] = f2bf(u);
        }
    } else {
#pragma unroll
        for (int j = 0; j < 8; ++j) o[j] = 0;
        if (c8 == HID) o[0] = 0x3F80;   // bf16(1.0) ones column
    }
    *(ushort8*)(h1 + (size_t)r * HROW + c8) = o;
}

// pad columns 512..543 of an h buffer (ones col + zeros)
__global__ __launch_bounds__(256)
void pad_h(unsigned short* __restrict__ h)
{
    const int idx = blockIdx.x * 256 + threadIdx.x;   // M2*4
    if (idx >= M2 * 4) return;
    const int r = idx >> 2, seg = idx & 3;
    ushort8 o;
#pragma unroll
    for (int j = 0; j < 8; ++j) o[j] = 0;
    if (seg == 0) o[0] = 0x3F80;
    *(ushort8*)(h + (size_t)r * HROW + HID + seg * 8) = o;
}

// Layer 4: per-wave dot products (N=10) + fused log_softmax; h3 is bf16 [M2 x 544]
__global__ __launch_bounds__(256)
void layer4(const unsigned short* __restrict__ h3, const float* __restrict__ Wm,
            const float* __restrict__ Ws, const float* __restrict__ eps4,
            float* __restrict__ out)
{
    const int wave = (int)((blockIdx.x * 256 + threadIdx.x) >> 6);
    const int lane = threadIdx.x & 63;
    if (wave >= M2) return;

    const unsigned short* x = h3 + (size_t)wave * HROW;
    float am[NC] = {}, as[NC] = {};
    for (int k = lane; k < HP; k += 64) {
        const float xv = bf2f(x[k]);
        const float xs = xv * xv;
#pragma unroll
        for (int c = 0; c < NC; ++c) {
            am[c] = fmaf(xv, Wm[k * NC + c], am[c]);
            const float s = Ws[k * NC + c];
            as[c] = fmaf(xs, s * s, as[c]);
        }
    }
#pragma unroll
    for (int off = 32; off; off >>= 1) {
#pragma unroll
        for (int c = 0; c < NC; ++c) {
            am[c] += __shfl_xor(am[c], off, 64);
            as[c] += __shfl_xor(as[c], off, 64);
        }
    }
    if (lane == 0) {
        float logit[NC];
        float mx = -1e30f;
#pragma unroll
        for (int c = 0; c < NC; ++c) {
            const float sg = sqrtf(as[c] + 1e-12f);
            logit[c] = am[c] + sg * eps4[(size_t)wave * NC + c];
            mx = fmaxf(mx, logit[c]);
        }
        float sum = 0.0f;
#pragma unroll
        for (int c = 0; c < NC; ++c) sum += expf(logit[c] - mx);
        const float lse = mx + logf(sum);
#pragma unroll
        for (int c = 0; c < NC; ++c) out[(size_t)wave * NC + c] = logit[c] - lse;
    }
}

// ---------------------------------------------------------------------------
extern "C" void kernel_launch(void* const* d_in, const int* in_sizes, int n_in,
                              void* d_out, int out_size, void* d_ws, size_t ws_size,
                              hipStream_t stream)
{
    const float* inputs   = (const float*)d_in[0];
    const float* a1_mean  = (const float*)d_in[1];
    const float* a1_scale = (const float*)d_in[2];
    const float* a1_drop  = (const float*)d_in[3];
    const float* a2_mean  = (const float*)d_in[4];
    const float* a2_scale = (const float*)d_in[5];
    const float* a2_drop  = (const float*)d_in[6];
    const float* a3_mean  = (const float*)d_in[7];
    const float* a3_scale = (const float*)d_in[8];
    const float* a3_drop  = (const float*)d_in[9];
    const float* a4_mean  = (const float*)d_in[10];
    const float* a4_scale = (const float*)d_in[11];
    const float* eps1     = (const float*)d_in[12];
    const float* eps2     = (const float*)d_in[13];
    const float* eps3     = (const float*)d_in[14];
    const float* eps4     = (const float*)d_in[15];
    float* out = (float*)d_out;

    char* p = (char*)d_ws;
    unsigned short* h_a  = (unsigned short*)p; p += (size_t)M2 * HROW * 2;
    unsigned short* h_b  = (unsigned short*)p; p += (size_t)M2 * HROW * 2;
    unsigned short* xb   = (unsigned short*)p; p += (size_t)BATCH * KP1 * 2;
    unsigned short* WT1m = (unsigned short*)p; p += (size_t)HID * KP1 * 2;
    unsigned short* WT1s = (unsigned short*)p; p += (size_t)HID * KP1 * 2;
    unsigned short* WT2m = (unsigned short*)p; p += (size_t)HID * KP2 * 2;
    unsigned short* WT2s = (unsigned short*)p; p += (size_t)HID * KP2 * 2;
    unsigned short* WT3m = (unsigned short*)p; p += (size_t)HID * KP2 * 2;
    unsigned short* WT3s = (unsigned short*)p; p += (size_t)HID * KP2 * 2;
    float* mu1 = (float*)p; p += (size_t)BATCH * HID * 4;
    float* sg1 = (float*)p; p += (size_t)BATCH * HID * 4;

    // pack / convert
    convert_x<<<(BATCH * 100 + 255) / 256, 256, 0, stream>>>(inputs, xb);
    pack_wT<<<dim3(KP1 / 32, HID / 32), dim3(32, 8), 0, stream>>>(a1_mean, a1_scale, a1_drop, DIN, KP1, WT1m, WT1s);
    pack_wT<<<dim3(KP2 / 32, HID / 32), dim3(32, 8), 0, stream>>>(a2_mean, a2_scale, a2_drop, HP, KP2, WT2m, WT2s);
    pack_wT<<<dim3(KP2 / 32, HID / 32), dim3(32, 8), 0, stream>>>(a3_mean, a3_scale, a3_drop, HP, KP2, WT3m, WT3s);
    pad_h<<<(M2 * 4 + 255) / 256, 256, 0, stream>>>(h_b);

    // layer 1 (sample-shared): mu1/sg1 [2048 x 512]
    dual_gemm_mfma<<<dim3(HID / 64, BATCH / 64), 256, 0, stream>>>(
        xb, WT1m, WT1s, KP1, nullptr, nullptr, mu1, sg1);

    // expand to h1 [20480 x 544] (incl ones + zero pad)
    expand1<<<(M2 * 68 + 255) / 256, 256, 0, stream>>>(mu1, sg1, eps1, h_a);

    // layer 2 fused -> h_b
    dual_gemm_mfma<<<dim3(HID / 64, M2 / 64), 256, 0, stream>>>(
        h_a, WT2m, WT2s, KP2, eps2, h_b, nullptr, nullptr);

    // layer 3 fused -> h_a (pad cols survive from expand1)
    dual_gemm_mfma<<<dim3(HID / 64, M2 / 64), 256, 0, stream>>>(
        h_b, WT3m, WT3s, KP2, eps3, h_a, nullptr, nullptr);

    // layer 4 + log_softmax
    layer4<<<(M2 * 64 + 255) / 256, 256, 0, stream>>>(h_a, a4_mean, a4_scale, eps4, out);
}

// Round 5
// 390.179 us; speedup vs baseline: 3.2138x; 1.0134x over previous
//
#include <hip/hip_runtime.h>
#include <math.h>

#define BATCH 2048
#define DIN   784
#define HID   512
#define NC    10
#define NS    10

constexpr int HP  = HID + 1;        // 513
constexpr int M2  = NS * BATCH;     // 20480
constexpr int KP2 = 544;            // 513 padded to 17*32
constexpr int KP1 = 800;            // 784 padded to 25*32
constexpr int HROW = 544;           // padded h row length (bf16)

typedef __attribute__((ext_vector_type(8))) short          short8;
typedef __attribute__((ext_vector_type(8))) unsigned short ushort8;
typedef __attribute__((ext_vector_type(4))) float          floatx4;

__device__ inline unsigned short f2bf(float f) {
    unsigned u = __builtin_bit_cast(unsigned, f);
    u += 0x7FFFu + ((u >> 16) & 1u);
    return (unsigned short)(u >> 16);
}
__device__ inline float bf2f(unsigned short u) {
    return __builtin_bit_cast(float, (unsigned)u << 16);
}

// square each of 8 bf16 lanes; repack via v_perm_b32 (5 insts/dword)
__device__ inline short8 sq8(short8 a) {
    union { short8 s; unsigned u[4]; } x;
    x.s = a;
#pragma unroll
    for (int i = 0; i < 4; ++i) {
        unsigned t = x.u[i];
        float lo = __builtin_bit_cast(float, t << 16);
        float hi = __builtin_bit_cast(float, t & 0xFFFF0000u);
        unsigned lq = __builtin_bit_cast(unsigned, lo * lo);
        unsigned hq = __builtin_bit_cast(unsigned, hi * hi);
        // D = {hq[31:16], lq[31:16]}  (bytes: lq.b2, lq.b3, hq.b2, hq.b3)
        x.u[i] = __builtin_amdgcn_perm(hq, lq, 0x07060302u);
    }
    return x.s;
}

#define GLOAD_LDS16(g, l)                                                      \
    __builtin_amdgcn_global_load_lds(                                          \
        (const __attribute__((address_space(1))) void*)(g),                    \
        (__attribute__((address_space(3))) void*)(l), 16, 0, 0)

// ---------------------------------------------------------------------------
// Dual MFMA GEMM: accm = A@Wm, accs = (A.*A)@Ws2.
// A bf16 [M x Kp]; weights pre-transposed bf16 [512 x Kp].
// Block tile 64(M) x 64(N); wave w computes rows [16w,16w+16) x all 64 cols.
// A fragment loaded DIRECTLY global->VGPR (1 dwordx4/thread/ktile, pipelined
// one iteration ahead); squared in-register once (not 4x as when waves slice N).
// B (m & s2) double-buffered in LDS via global_load_lds. eps tile (64x64 f32)
// DMA'd into LDS during first 4 ktiles.
// ---------------------------------------------------------------------------
__global__ __launch_bounds__(256)
void dual_gemm_mfma(const unsigned short* __restrict__ A,
                    const unsigned short* __restrict__ WTm,
                    const unsigned short* __restrict__ WTs2,
                    int Kp,
                    const float* __restrict__ eps,
                    unsigned short* __restrict__ hout,
                    float* __restrict__ mu_out,
                    float* __restrict__ sg_out)
{
    // B buf0 8K | B buf1 8K | eps 16K = 32 KB -> 5 blocks/CU
    __shared__ __align__(16) char smem[32768];
    float* epsL = (float*)(smem + 16384);

    const int tid  = threadIdx.x;        // 0..255
    const int lane = tid & 63;
    const int w    = tid >> 6;           // wave 0..3 -> 16-row slice
    const int quad = lane >> 4;
    const int l16  = lane & 15;

    const int row0 = blockIdx.y * 64;
    const int col0 = blockIdx.x * 64;

    const size_t KpB = (size_t)Kp * 2;
    const char* gBm = (const char*)(WTm  + (size_t)col0 * Kp);
    const char* gBs = (const char*)(WTs2 + (size_t)col0 * Kp);
    const float* gE = eps ? (eps + (size_t)row0 * HID + col0) : nullptr;
    // this lane's A row/quad base: row = row0 + w*16 + l16, k-offset quad*8
    const char* gAl = (const char*)(A + (size_t)(row0 + w * 16 + l16) * Kp) + quad * 16;

    // B staging: 64 n-rows x 32 k x 2B = 4 KB each = 256 x 16B chunks
    const int sr = tid >> 2, ss = tid & 3;
    auto stageB = [&](int kt, char* buf) {
        const size_t go = (size_t)sr * KpB + (size_t)kt * 64 + ss * 16;
        GLOAD_LDS16(gBm + go, buf + tid * 16);
        GLOAD_LDS16(gBs + go, buf + 4096 + tid * 16);
    };

    stageB(0, smem);
    short8 aCur = *(const short8*)(gAl);

    floatx4 accm[4] = {};
    floatx4 accs[4] = {};

    const int ktiles = Kp >> 5;
    for (int kt = 0; kt < ktiles; ++kt) {
        __syncthreads();   // drains B(kt) + aCur (both issued last iter)
        char* cur = smem + (kt & 1) * 8192;
        if (kt + 1 < ktiles) stageB(kt + 1, smem + ((kt + 1) & 1) * 8192);
        if (gE != nullptr && kt < 4) {
            const int c2 = kt * 256 + tid;              // 16B chunk of eps tile
            const int r = c2 >> 4, s = c2 & 15;
            GLOAD_LDS16(gE + (size_t)r * HID + s * 4, (char*)epsL + (size_t)c2 * 16);
        }
        const int kNext = (kt + 1 < ktiles) ? kt + 1 : kt;
        short8 aNext = *(const short8*)(gAl + (size_t)kNext * 64);

        const short8 q = sq8(aCur);
#pragma unroll
        for (int j = 0; j < 4; ++j) {
            const int off = ((j * 16 + l16) * 32 + quad * 8) * 2;
            const short8 bm = *(const short8*)(cur + off);
            const short8 bs = *(const short8*)(cur + 4096 + off);
            accm[j] = __builtin_amdgcn_mfma_f32_16x16x32_bf16(aCur, bm, accm[j], 0, 0, 0);
            accs[j] = __builtin_amdgcn_mfma_f32_16x16x32_bf16(q,    bs, accs[j], 0, 0, 0);
        }
        aCur = aNext;
    }

    // epilogue: C/D layout col=lane&15, row=quad*4+reg; wave w owns 16 rows
    if (eps != nullptr) {
#pragma unroll
        for (int j = 0; j < 4; ++j) {
#pragma unroll
            for (int r = 0; r < 4; ++r) {
                const int rl = w * 16 + quad * 4 + r;
                const int cl = j * 16 + l16;
                const float sg = sqrtf(accs[j][r] + 1e-12f);
                float v = accm[j][r] + sg * epsL[rl * 64 + cl];
                v = v > 0.0f ? v : 0.01f * v;
                hout[(size_t)(row0 + rl) * HROW + col0 + cl] = f2bf(v);
            }
        }
    } else {
#pragma unroll
        for (int j = 0; j < 4; ++j) {
#pragma unroll
            for (int r = 0; r < 4; ++r) {
                const int rl = w * 16 + quad * 4 + r;
                const int cl = j * 16 + l16;
                const size_t o = (size_t)(row0 + rl) * HID + col0 + cl;
                mu_out[o] = accm[j][r];
                sg_out[o] = sqrtf(accs[j][r] + 1e-12f);
            }
        }
    }
}

// ---------------------------------------------------------------------------
// Weight pack: WTm[n][k] = bf16(Wm[k][n]); WTs2[n][k] = bf16((drop*Ws[k][n])^2)
// ---------------------------------------------------------------------------
__global__ __launch_bounds__(256)
void pack_wT(const float* __restrict__ Wm, const float* __restrict__ Ws,
             const float* __restrict__ dropPtr, int K, int Kp,
             unsigned short* __restrict__ WTm, unsigned short* __restrict__ WTs2)
{
    __shared__ float tm[32][33];
    __shared__ float ts[32][33];
    const float drop = dropPtr[0];
    const int k0 = blockIdx.x * 32, n0 = blockIdx.y * 32;
    const int tx = threadIdx.x, ty = threadIdx.y;   // 32 x 8
#pragma unroll
    for (int i = 0; i < 4; ++i) {
        const int k = k0 + ty + 8 * i;
        float m = 0.0f, s2 = 0.0f;
        if (k < K) {
            m = Wm[(size_t)k * HID + n0 + tx];
            const float s = Ws[(size_t)k * HID + n0 + tx] * drop;
            s2 = s * s;
        }
        tm[ty + 8 * i][tx] = m;
        ts[ty + 8 * i][tx] = s2;
    }
    __syncthreads();
#pragma unroll
    for (int i = 0; i < 4; ++i) {
        const int n = n0 + ty + 8 * i;
        WTm[(size_t)n * Kp + k0 + tx]  = f2bf(tm[tx][ty + 8 * i]);
        WTs2[(size_t)n * Kp + k0 + tx] = f2bf(ts[tx][ty + 8 * i]);
    }
}

// convert inputs f32 [2048 x 784] -> bf16 [2048 x 800] zero-padded
__global__ __launch_bounds__(256)
void convert_x(const float* __restrict__ x, unsigned short* __restrict__ xb)
{
    const int idx = blockIdx.x * 256 + threadIdx.x;   // 2048*100
    if (idx >= BATCH * 100) return;
    const int r = idx / 100;
    const int c8 = (idx - r * 100) * 8;
    ushort8 o;
    if (c8 < DIN) {   // DIN=784=98*8
        const floatx4 a = *(const floatx4*)(x + (size_t)r * DIN + c8);
        const floatx4 b = *(const floatx4*)(x + (size_t)r * DIN + c8 + 4);
#pragma unroll
        for (int j = 0; j < 4; ++j) { o[j] = f2bf(a[j]); o[4 + j] = f2bf(b[j]); }
    } else {
#pragma unroll
        for (int j = 0; j < 8; ++j) o[j] = 0;
    }
    *(ushort8*)(xb + (size_t)r * KP1 + c8) = o;
}

// h1[r][c] = bf16(leaky(mu1[b][c] + sg1[b][c]*eps1[r][c])), full 544-row incl pad
__global__ __launch_bounds__(256)
void expand1(const float* __restrict__ mu1, const float* __restrict__ sg1,
             const float* __restrict__ eps1, unsigned short* __restrict__ h1)
{
    const int idx = blockIdx.x * 256 + threadIdx.x;   // M2*68
    if (idx >= M2 * 68) return;
    const int r  = idx / 68;
    const int c8 = (idx - r * 68) * 8;
    ushort8 o;
    if (c8 < HID) {
        const int b = r & (BATCH - 1);
        const floatx4* ep = (const floatx4*)(eps1 + (size_t)r * HID + c8);
        const floatx4* mp = (const floatx4*)(mu1 + (size_t)b * HID + c8);
        const floatx4* sp = (const floatx4*)(sg1 + (size_t)b * HID + c8);
        const floatx4 e0 = ep[0], e1 = ep[1];
        const floatx4 m0 = mp[0], m1 = mp[1];
        const floatx4 s0 = sp[0], s1 = sp[1];
#pragma unroll
        for (int j = 0; j < 4; ++j) {
            float v = m0[j] + s0[j] * e0[j];
            v = v > 0.0f ? v : 0.01f * v;
            o[j] = f2bf(v);
            float u = m1[j] + s1[j] * e1[j];
            u = u > 0.0f ? u : 0.01f * u;
            o[4 + j] = f2bf(u);
        }
    } else {
#pragma unroll
        for (int j = 0; j < 8; ++j) o[j] = 0;
        if (c8 == HID) o[0] = 0x3F80;   // bf16(1.0) ones column
    }
    *(ushort8*)(h1 + (size_t)r * HROW + c8) = o;
}

// pad columns 512..543 of an h buffer (ones col + zeros)
__global__ __launch_bounds__(256)
void pad_h(unsigned short* __restrict__ h)
{
    const int idx = blockIdx.x * 256 + threadIdx.x;   // M2*4
    if (idx >= M2 * 4) return;
    const int r = idx >> 2, seg = idx & 3;
    ushort8 o;
#pragma unroll
    for (int j = 0; j < 8; ++j) o[j] = 0;
    if (seg == 0) o[0] = 0x3F80;
    *(ushort8*)(h + (size_t)r * HROW + HID + seg * 8) = o;
}

// Layer 4: per-wave dot products (N=10) + fused log_softmax; h3 is bf16 [M2 x 544]
__global__ __launch_bounds__(256)
void layer4(const unsigned short* __restrict__ h3, const float* __restrict__ Wm,
            const float* __restrict__ Ws, const float* __restrict__ eps4,
            float* __restrict__ out)
{
    const int wave = (int)((blockIdx.x * 256 + threadIdx.x) >> 6);
    const int lane = threadIdx.x & 63;
    if (wave >= M2) return;

    const unsigned short* x = h3 + (size_t)wave * HROW;
    float am[NC] = {}, as[NC] = {};
    for (int k = lane; k < HP; k += 64) {
        const float xv = bf2f(x[k]);
        const float xs = xv * xv;
#pragma unroll
        for (int c = 0; c < NC; ++c) {
            am[c] = fmaf(xv, Wm[k * NC + c], am[c]);
            const float s = Ws[k * NC + c];
            as[c] = fmaf(xs, s * s, as[c]);
        }
    }
#pragma unroll
    for (int off = 32; off; off >>= 1) {
#pragma unroll
        for (int c = 0; c < NC; ++c) {
            am[c] += __shfl_xor(am[c], off, 64);
            as[c] += __shfl_xor(as[c], off, 64);
        }
    }
    if (lane == 0) {
        float logit[NC];
        float mx = -1e30f;
#pragma unroll
        for (int c = 0; c < NC; ++c) {
            const float sg = sqrtf(as[c] + 1e-12f);
            logit[c] = am[c] + sg * eps4[(size_t)wave * NC + c];
            mx = fmaxf(mx, logit[c]);
        }
        float sum = 0.0f;
#pragma unroll
        for (int c = 0; c < NC; ++c) sum += expf(logit[c] - mx);
        const float lse = mx + logf(sum);
#pragma unroll
        for (int c = 0; c < NC; ++c) out[(size_t)wave * NC + c] = logit[c] - lse;
    }
}

// ---------------------------------------------------------------------------
extern "C" void kernel_launch(void* const* d_in, const int* in_sizes, int n_in,
                              void* d_out, int out_size, void* d_ws, size_t ws_size,
                              hipStream_t stream)
{
    const float* inputs   = (const float*)d_in[0];
    const float* a1_mean  = (const float*)d_in[1];
    const float* a1_scale = (const float*)d_in[2];
    const float* a1_drop  = (const float*)d_in[3];
    const float* a2_mean  = (const float*)d_in[4];
    const float* a2_scale = (const float*)d_in[5];
    const float* a2_drop  = (const float*)d_in[6];
    const float* a3_mean  = (const float*)d_in[7];
    const float* a3_scale = (const float*)d_in[8];
    const float* a3_drop  = (const float*)d_in[9];
    const float* a4_mean  = (const float*)d_in[10];
    const float* a4_scale = (const float*)d_in[11];
    const float* eps1     = (const float*)d_in[12];
    const float* eps2     = (const float*)d_in[13];
    const float* eps3     = (const float*)d_in[14];
    const float* eps4     = (const float*)d_in[15];
    float* out = (float*)d_out;

    char* p = (char*)d_ws;
    unsigned short* h_a  = (unsigned short*)p; p += (size_t)M2 * HROW * 2;
    unsigned short* h_b  = (unsigned short*)p; p += (size_t)M2 * HROW * 2;
    unsigned short* xb   = (unsigned short*)p; p += (size_t)BATCH * KP1 * 2;
    unsigned short* WT1m = (unsigned short*)p; p += (size_t)HID * KP1 * 2;
    unsigned short* WT1s = (unsigned short*)p; p += (size_t)HID * KP1 * 2;
    unsigned short* WT2m = (unsigned short*)p; p += (size_t)HID * KP2 * 2;
    unsigned short* WT2s = (unsigned short*)p; p += (size_t)HID * KP2 * 2;
    unsigned short* WT3m = (unsigned short*)p; p += (size_t)HID * KP2 * 2;
    unsigned short* WT3s = (unsigned short*)p; p += (size_t)HID * KP2 * 2;
    float* mu1 = (float*)p; p += (size_t)BATCH * HID * 4;
    float* sg1 = (float*)p; p += (size_t)BATCH * HID * 4;

    // pack / convert
    convert_x<<<(BATCH * 100 + 255) / 256, 256, 0, stream>>>(inputs, xb);
    pack_wT<<<dim3(KP1 / 32, HID / 32), dim3(32, 8), 0, stream>>>(a1_mean, a1_scale, a1_drop, DIN, KP1, WT1m, WT1s);
    pack_wT<<<dim3(KP2 / 32, HID / 32), dim3(32, 8), 0, stream>>>(a2_mean, a2_scale, a2_drop, HP, KP2, WT2m, WT2s);
    pack_wT<<<dim3(KP2 / 32, HID / 32), dim3(32, 8), 0, stream>>>(a3_mean, a3_scale, a3_drop, HP, KP2, WT3m, WT3s);
    pad_h<<<(M2 * 4 + 255) / 256, 256, 0, stream>>>(h_b);

    // layer 1 (sample-shared): mu1/sg1 [2048 x 512]
    dual_gemm_mfma<<<dim3(HID / 64, BATCH / 64), 256, 0, stream>>>(
        xb, WT1m, WT1s, KP1, nullptr, nullptr, mu1, sg1);

    // expand to h1 [20480 x 544] (incl ones + zero pad)
    expand1<<<(M2 * 68 + 255) / 256, 256, 0, stream>>>(mu1, sg1, eps1, h_a);

    // layer 2 fused -> h_b
    dual_gemm_mfma<<<dim3(HID / 64, M2 / 64), 256, 0, stream>>>(
        h_a, WT2m, WT2s, KP2, eps2, h_b, nullptr, nullptr);

    // layer 3 fused -> h_a (pad cols survive from expand1)
    dual_gemm_mfma<<<dim3(HID / 64, M2 / 64), 256, 0, stream>>>(
        h_b, WT3m, WT3s, KP2, eps3, h_a, nullptr, nullptr);

    // layer 4 + log_softmax
    layer4<<<(M2 * 64 + 255) / 256, 256, 0, stream>>>(h_a, a4_mean, a4_scale, eps4, out);
}